// Round 12
// baseline (61.289 us; speedup 1.0000x reference)
//
#include <hip/hip_runtime.h>
#include <math.h>

#define SEQ_LEN 4096
#define KSZ 128
#define OUT_LEN 3969
#define BATCH 8192
#define NB_MAIN 256      // main grid: 1 block per CU
#define NWAVES 16        // 1024 threads per block

// ---- DPP wave-64 sum, result broadcast wave-uniform via readlane 63 ----
// (A/B verified R6 vs R8: ~2us faster than shfl_xor butterfly.)
template <int CTRL>
__device__ __forceinline__ float dpp_add(float x) {
    const int m = __builtin_amdgcn_update_dpp(0, __float_as_int(x), CTRL, 0xf, 0xf, true);
    return x + __int_as_float(m);
}
__device__ __forceinline__ float wave_sum_uniform(float x) {
    x = dpp_add<0x111>(x);   // row_shr:1
    x = dpp_add<0x112>(x);   // row_shr:2
    x = dpp_add<0x114>(x);   // row_shr:4
    x = dpp_add<0x118>(x);   // row_shr:8
    x = dpp_add<0x142>(x);   // row_bcast:15
    x = dpp_add<0x143>(x);   // row_bcast:31
    return __int_as_float(__builtin_amdgcn_readlane(__float_as_int(x), 63));
}

// Main pass (R10/R11, byte-identical): 256 blocks x 1024 threads.
// THIS ROUND: dispatched TWICE as a timing probe (R7 method). The second
// run recomputes bit-identical partials (idempotent, deterministic).
// fat_main + node = T(R12) - T(R11).
__global__ __launch_bounds__(1024)
__attribute__((amdgpu_waves_per_eu(4, 4)))
void conv1d_train_main(
    const float* __restrict__ x, const float* __restrict__ y,
    const float* __restrict__ kern, const float* __restrict__ bias,
    float* __restrict__ partial)
{
    __shared__ float P[KSZ];          // inclusive prefix sums of kernel
    __shared__ float sl[NWAVES][256]; // per-wave partials for block combine

    const int tid  = threadIdx.x;
    const int wave = tid >> 6;
    const int lane = tid & 63;

    if (tid < KSZ) P[tid] = kern[tid];
    __syncthreads();
#pragma unroll
    for (int off = 1; off < KSZ; off <<= 1) {   // Hillis-Steele scan
        float v = 0.f;
        if (tid < KSZ) {
            v = P[tid];
            if (tid >= off) v += P[tid - off];
        }
        __syncthreads();
        if (tid < KSZ) P[tid] = v;
        __syncthreads();
    }
    const float ksum = P[KSZ - 1];
    const float bs   = bias[0];

    // Per-lane edge-correction weights (verified R2).
    // head lane l<32: elems j=4l..4l+3, weight P[j]-ksum  (j=127 -> 0)
    // tail lane l>=32: elem 3968+4(l-32)+q, m=elem-3969, weight -P[m]; m=-1 -> 0
    float w0, w1, w2, w3;
    if (lane < 32) {
        const int j = 4 * lane;
        w0 = P[j] - ksum; w1 = P[j + 1] - ksum;
        w2 = P[j + 2] - ksum; w3 = P[j + 3] - ksum;
    } else {
        const int m = 4 * (lane - 32) - 1;
        w0 = (m >= 0) ? -P[m] : 0.f;
        w1 = -P[m + 1]; w2 = -P[m + 2]; w3 = -P[m + 3];
    }

    float g0 = 0.f, g1 = 0.f, g2 = 0.f, g3 = 0.f;  // dconv-weighted edge accum
    float C0 = 0.f, db = 0.f;

    const int wg = blockIdx.x * NWAVES + wave;       // 0..4095

    for (int b = wg; b < BATCH; b += NB_MAIN * NWAVES) {   // 2 iterations
        const float4* xr = reinterpret_cast<const float4*>(x + (size_t)b * SEQ_LEN);
        float4 r[16];
#pragma unroll
        for (int i = 0; i < 16; ++i) r[i] = xr[i * 64 + lane];
        const float yv = y[b];                       // broadcast load

        float tot = 0.f;
#pragma unroll
        for (int i = 0; i < 16; ++i) tot += (r[i].x + r[i].y) + (r[i].z + r[i].w);

        const float4 e = (lane < 32) ? r[0] : r[15];
        const float corr = ((w0 * e.x + w1 * e.y) + (w2 * e.z + w3 * e.w));

        const float t = wave_sum_uniform(tot);       // wave-uniform scalars
        const float c = wave_sum_uniform(corr);

        const float logits = (ksum * t + c) * (1.f / (float)OUT_LEN) + bs;
        const float sig    = 1.f / (1.f + expf(-logits));
        const float dconv  = (sig - yv) * (1.f / (float)OUT_LEN);

        g0 += dconv * e.x; g1 += dconv * e.y;
        g2 += dconv * e.z; g3 += dconv * e.w;
        C0 += dconv * t;   db += dconv;
    }

    // Per-wave writeout to LDS: [0..126]=G, [127]=C0, [128..254]=H, [255]=db
    if (lane < 32) {
        const int j = 4 * lane;
        sl[wave][j]     = g0;
        sl[wave][j + 1] = g1;
        sl[wave][j + 2] = g2;
        if (j + 3 < 127) sl[wave][j + 3] = g3;   // skip unused G[127]
    } else {
        const int s0 = 4 * lane - 1;             // slot = 128 + m
        if (lane > 32) sl[wave][s0] = g0;        // lane 32 q=0 -> m=-1, skip
        sl[wave][s0 + 1] = g1;
        sl[wave][s0 + 2] = g2;
        sl[wave][s0 + 3] = g3;                   // lane 63 -> slot 254
    }
    if (lane == 0) { sl[wave][127] = C0; sl[wave][255] = db; }
    __syncthreads();
    if (tid < 256) {
        float s = 0.f;
#pragma unroll
        for (int w = 0; w < NWAVES; ++w) s += sl[w][tid];
        partial[(size_t)blockIdx.x * 256 + tid] = s;   // coalesced 1KB/block
    }
}

// Tail (R11, byte-identical): float4 loads, one block, 1024 threads.
__global__ __launch_bounds__(1024) void conv1d_train_tail(
    const float* __restrict__ partial,
    const float* __restrict__ kern, const float* __restrict__ bias,
    float* __restrict__ out)
{
    __shared__ float slr[NWAVES][256];
    __shared__ float colsum[256];

    const int tid   = threadIdx.x;
    const int k     = tid & 63;                 // column group -> cols 4k..4k+3
    const int slice = tid >> 6;                 // 0..15, 16 rows each
    const int rbase = slice * 16;

    float4 a0 = {0.f, 0.f, 0.f, 0.f}, a1 = {0.f, 0.f, 0.f, 0.f};
    float4 a2 = {0.f, 0.f, 0.f, 0.f}, a3 = {0.f, 0.f, 0.f, 0.f};
    const float4* p4 = reinterpret_cast<const float4*>(partial);
#pragma unroll
    for (int j = 0; j < 16; j += 4) {           // 4 independent chains
        const float4 v0 = p4[(size_t)(rbase + j + 0) * 64 + k];
        const float4 v1 = p4[(size_t)(rbase + j + 1) * 64 + k];
        const float4 v2 = p4[(size_t)(rbase + j + 2) * 64 + k];
        const float4 v3 = p4[(size_t)(rbase + j + 3) * 64 + k];
        a0.x += v0.x; a0.y += v0.y; a0.z += v0.z; a0.w += v0.w;
        a1.x += v1.x; a1.y += v1.y; a1.z += v1.z; a1.w += v1.w;
        a2.x += v2.x; a2.y += v2.y; a2.z += v2.z; a2.w += v2.w;
        a3.x += v3.x; a3.y += v3.y; a3.z += v3.z; a3.w += v3.w;
    }
    float4 a;
    a.x = (a0.x + a1.x) + (a2.x + a3.x);
    a.y = (a0.y + a1.y) + (a2.y + a3.y);
    a.z = (a0.z + a1.z) + (a2.z + a3.z);
    a.w = (a0.w + a1.w) + (a2.w + a3.w);
    slr[slice][4 * k + 0] = a.x;
    slr[slice][4 * k + 1] = a.y;
    slr[slice][4 * k + 2] = a.z;
    slr[slice][4 * k + 3] = a.w;
    __syncthreads();

    if (tid < 256) {
        float s = 0.f;
#pragma unroll
        for (int w = 0; w < NWAVES; ++w) s += slr[w][tid];
        colsum[tid] = s;
    }
    __syncthreads();

    if (tid < 128) {
        const float C0 = colsum[127];
        float pre = 0.f, suf = 0.f;
        for (int j = 0; j < 127; ++j) {
            const float g = colsum[j];           // broadcast
            const float h = colsum[128 + j];
            if (j < tid)  pre += g;
            if (j >= tid) suf += h;
        }
        const float dk = (C0 - pre - suf) * (1.f / (float)BATCH);
        out[tid] = kern[tid] - dk;
    }
    if (tid == 0) {
        const float db = colsum[255] * ((float)OUT_LEN / (float)BATCH);
        out[128] = bias[0] - db;
    }
}

extern "C" void kernel_launch(void* const* d_in, const int* in_sizes, int n_in,
                              void* d_out, int out_size, void* d_ws, size_t ws_size,
                              hipStream_t stream) {
    (void)in_sizes; (void)n_in; (void)out_size; (void)ws_size;
    const float* x    = (const float*)d_in[0];
    const float* y    = (const float*)d_in[1];
    const float* kern = (const float*)d_in[2];
    const float* bias = (const float*)d_in[3];
    float* out = (float*)d_out;

    float* partial = (float*)d_ws;

    // TIMING PROBE (R7 method): fat main launched twice; second run
    // rewrites bit-identical partials. fat_main + node = T(R12) - T(R11).
    hipLaunchKernelGGL(conv1d_train_main, dim3(NB_MAIN), dim3(1024), 0, stream,
                       x, y, kern, bias, partial);
    hipLaunchKernelGGL(conv1d_train_main, dim3(NB_MAIN), dim3(1024), 0, stream,
                       x, y, kern, bias, partial);
    hipLaunchKernelGGL(conv1d_train_tail, dim3(1), dim3(1024), 0, stream,
                       partial, kern, bias, out);
}

// Round 13
// 38.330 us; speedup vs baseline: 1.5990x; 1.5990x over previous
//
#include <hip/hip_runtime.h>
#include <math.h>

#define SEQ_LEN 4096
#define KSZ 128
#define OUT_LEN 3969
#define BATCH 8192
#define NB_MAIN 256      // main grid: 1 block per CU
#define NWAVES 16        // 1024 threads per block
#define TAIL_NB 16       // tail blocks (one accum slot each)

// ---- DPP wave-64 sum, result broadcast wave-uniform via readlane 63 ----
// (A/B verified R6 vs R8: ~2us faster than shfl_xor butterfly.)
template <int CTRL>
__device__ __forceinline__ float dpp_add(float x) {
    const int m = __builtin_amdgcn_update_dpp(0, __float_as_int(x), CTRL, 0xf, 0xf, true);
    return x + __int_as_float(m);
}
__device__ __forceinline__ float wave_sum_uniform(float x) {
    x = dpp_add<0x111>(x);   // row_shr:1
    x = dpp_add<0x112>(x);   // row_shr:2
    x = dpp_add<0x114>(x);   // row_shr:4
    x = dpp_add<0x118>(x);   // row_shr:8
    x = dpp_add<0x142>(x);   // row_bcast:15
    x = dpp_add<0x143>(x);   // row_bcast:31
    return __int_as_float(__builtin_amdgcn_readlane(__float_as_int(x), 63));
}

// Main pass (R10/R11/R12, byte-identical; measured 22.4us incl node):
// 256 blocks x 1024 threads, 16 waves/CU. One wave = one row, 2 rows/wave,
// no barriers in the row loop, 16 float4 loads in flight, DPP reduce,
// edge gradients in registers. amdgpu_waves_per_eu(4,4) pins 128 VGPRs.
__global__ __launch_bounds__(1024)
__attribute__((amdgpu_waves_per_eu(4, 4)))
void conv1d_train_main(
    const float* __restrict__ x, const float* __restrict__ y,
    const float* __restrict__ kern, const float* __restrict__ bias,
    float* __restrict__ partial)
{
    __shared__ float P[KSZ];          // inclusive prefix sums of kernel
    __shared__ float sl[NWAVES][256]; // per-wave partials for block combine

    const int tid  = threadIdx.x;
    const int wave = tid >> 6;
    const int lane = tid & 63;

    if (tid < KSZ) P[tid] = kern[tid];
    __syncthreads();
#pragma unroll
    for (int off = 1; off < KSZ; off <<= 1) {   // Hillis-Steele scan
        float v = 0.f;
        if (tid < KSZ) {
            v = P[tid];
            if (tid >= off) v += P[tid - off];
        }
        __syncthreads();
        if (tid < KSZ) P[tid] = v;
        __syncthreads();
    }
    const float ksum = P[KSZ - 1];
    const float bs   = bias[0];

    // Per-lane edge-correction weights (verified R2).
    float w0, w1, w2, w3;
    if (lane < 32) {
        const int j = 4 * lane;
        w0 = P[j] - ksum; w1 = P[j + 1] - ksum;
        w2 = P[j + 2] - ksum; w3 = P[j + 3] - ksum;
    } else {
        const int m = 4 * (lane - 32) - 1;
        w0 = (m >= 0) ? -P[m] : 0.f;
        w1 = -P[m + 1]; w2 = -P[m + 2]; w3 = -P[m + 3];
    }

    float g0 = 0.f, g1 = 0.f, g2 = 0.f, g3 = 0.f;  // dconv-weighted edge accum
    float C0 = 0.f, db = 0.f;

    const int wg = blockIdx.x * NWAVES + wave;       // 0..4095

    for (int b = wg; b < BATCH; b += NB_MAIN * NWAVES) {   // 2 iterations
        const float4* xr = reinterpret_cast<const float4*>(x + (size_t)b * SEQ_LEN);
        float4 r[16];
#pragma unroll
        for (int i = 0; i < 16; ++i) r[i] = xr[i * 64 + lane];
        const float yv = y[b];                       // broadcast load

        float tot = 0.f;
#pragma unroll
        for (int i = 0; i < 16; ++i) tot += (r[i].x + r[i].y) + (r[i].z + r[i].w);

        const float4 e = (lane < 32) ? r[0] : r[15];
        const float corr = ((w0 * e.x + w1 * e.y) + (w2 * e.z + w3 * e.w));

        const float t = wave_sum_uniform(tot);       // wave-uniform scalars
        const float c = wave_sum_uniform(corr);

        const float logits = (ksum * t + c) * (1.f / (float)OUT_LEN) + bs;
        const float sig    = 1.f / (1.f + expf(-logits));
        const float dconv  = (sig - yv) * (1.f / (float)OUT_LEN);

        g0 += dconv * e.x; g1 += dconv * e.y;
        g2 += dconv * e.z; g3 += dconv * e.w;
        C0 += dconv * t;   db += dconv;
    }

    // Per-wave writeout to LDS: [0..126]=G, [127]=C0, [128..254]=H, [255]=db
    if (lane < 32) {
        const int j = 4 * lane;
        sl[wave][j]     = g0;
        sl[wave][j + 1] = g1;
        sl[wave][j + 2] = g2;
        if (j + 3 < 127) sl[wave][j + 3] = g3;   // skip unused G[127]
    } else {
        const int s0 = 4 * lane - 1;             // slot = 128 + m
        if (lane > 32) sl[wave][s0] = g0;        // lane 32 q=0 -> m=-1, skip
        sl[wave][s0 + 1] = g1;
        sl[wave][s0 + 2] = g2;
        sl[wave][s0 + 3] = g3;                   // lane 63 -> slot 254
    }
    if (lane == 0) { sl[wave][127] = C0; sl[wave][255] = db; }
    __syncthreads();
    if (tid < 256) {
        float s = 0.f;
#pragma unroll
        for (int w = 0; w < NWAVES; ++w) s += sl[w][tid];
        partial[(size_t)blockIdx.x * 256 + tid] = s;   // coalesced 1KB/block
    }
}

// Tail (single node, last-block-done WITHOUT accumulation): 16 blocks x
// 1024 threads. Block b reduces rows 16b..16b+15 of partial (16KB, one
// float4/thread) to a 256-float block sum and PUBLISHES it via atomicExch
// into its own slot accum[b][:] — overwrite semantics: no zeroing needed,
// immune to workspace poison, no contention, deterministic. tid0 fences +
// bumps the counter; the 16th arriver (exactly one per launch for any
// counter start: {v..v+15} contains exactly one ==15 mod 16) reads the
// 16x256 slots with agent-scope atomic loads, sums replicas in FIXED
// order (bit-deterministic), does the 127-step prefix/suffix scan, and
// writes kernel_new (128) + bias_new (1).
__global__ __launch_bounds__(1024) void conv1d_train_tail(
    const float* __restrict__ partial, float* __restrict__ accum,
    unsigned* __restrict__ counter,
    const float* __restrict__ kern, const float* __restrict__ bias,
    float* __restrict__ out)
{
    __shared__ float slr[NWAVES][256];
    __shared__ float colsum[256];
    __shared__ unsigned lastFlag;

    const int tid   = threadIdx.x;
    const int rsub  = tid >> 6;                 // 0..15 (row within block's 16)
    const int f4c   = tid & 63;                 // float4 column
    const int rbase = blockIdx.x * 16;

    // Phase A: one float4 per thread covers this block's 16 rows.
    const float4* p4 = reinterpret_cast<const float4*>(partial);
    const float4 v = p4[(size_t)(rbase + rsub) * 64 + f4c];
    slr[rsub][4 * f4c + 0] = v.x;
    slr[rsub][4 * f4c + 1] = v.y;
    slr[rsub][4 * f4c + 2] = v.z;
    slr[rsub][4 * f4c + 3] = v.w;
    __syncthreads();

    if (tid < 256) {
        float s = 0.f;
#pragma unroll
        for (int w = 0; w < NWAVES; ++w) s += slr[w][tid];
        atomicExch(&accum[(size_t)blockIdx.x * 256 + tid], s);  // publish
    }
    __syncthreads();            // drains vmcnt: exchanges retired

    if (tid == 0) {
        __threadfence();
        const unsigned old = atomicAdd(counter, 1u);
        lastFlag = ((old & 15u) == 15u) ? 1u : 0u;
    }
    __syncthreads();
    if (!lastFlag) return;

    // Last block: gather the 16 published slots (agent-scope atomic loads
    // bypass stale caches), fixed-order sum -> deterministic.
    if (tid < 256) {
        float s = 0.f;
#pragma unroll
        for (int w = 0; w < TAIL_NB; ++w)
            s += __hip_atomic_load(&accum[(size_t)w * 256 + tid],
                                   __ATOMIC_RELAXED, __HIP_MEMORY_SCOPE_AGENT);
        colsum[tid] = s;
    }
    __syncthreads();

    if (tid < 128) {
        const float C0 = colsum[127];
        float pre = 0.f, suf = 0.f;
        for (int j = 0; j < 127; ++j) {
            const float g = colsum[j];           // broadcast
            const float h = colsum[128 + j];
            if (j < tid)  pre += g;
            if (j >= tid) suf += h;
        }
        const float dk = (C0 - pre - suf) * (1.f / (float)BATCH);
        out[tid] = kern[tid] - dk;
    }
    if (tid == 0) {
        const float dbo = colsum[255] * ((float)OUT_LEN / (float)BATCH);
        out[128] = bias[0] - dbo;
    }
}

extern "C" void kernel_launch(void* const* d_in, const int* in_sizes, int n_in,
                              void* d_out, int out_size, void* d_ws, size_t ws_size,
                              hipStream_t stream) {
    (void)in_sizes; (void)n_in; (void)out_size; (void)ws_size;
    const float* x    = (const float*)d_in[0];
    const float* y    = (const float*)d_in[1];
    const float* kern = (const float*)d_in[2];
    const float* bias = (const float*)d_in[3];
    float* out = (float*)d_out;

    // ws layout: partial[256*256] floats (256KB), accum[16*256] floats
    // (16KB), counter (4B). partial/accum fully overwritten every launch;
    // counter works mod 16 for any start value — nothing needs init.
    float*    partial = (float*)d_ws;
    float*    accum   = partial + (size_t)NB_MAIN * 256;
    unsigned* counter = (unsigned*)(accum + (size_t)TAIL_NB * 256);

    hipLaunchKernelGGL(conv1d_train_main, dim3(NB_MAIN), dim3(1024), 0, stream,
                       x, y, kern, bias, partial);
    hipLaunchKernelGGL(conv1d_train_tail, dim3(TAIL_NB), dim3(1024), 0, stream,
                       partial, accum, counter, kern, bias, out);
}

// Round 14
// 31.263 us; speedup vs baseline: 1.9604x; 1.2261x over previous
//
#include <hip/hip_runtime.h>
#include <math.h>

#define SEQ_LEN 4096
#define KSZ 128
#define OUT_LEN 3969
#define BATCH 8192
#define NB_MAIN 256      // main grid: 1 block per CU
#define NWAVES 16        // 1024 threads per block
#define TAIL_NB 16       // tail blocks (one accum slot each)

// ---- DPP wave-64 sum, result broadcast wave-uniform via readlane 63 ----
// (A/B verified R6 vs R8: ~2us faster than shfl_xor butterfly.)
template <int CTRL>
__device__ __forceinline__ float dpp_add(float x) {
    const int m = __builtin_amdgcn_update_dpp(0, __float_as_int(x), CTRL, 0xf, 0xf, true);
    return x + __int_as_float(m);
}
__device__ __forceinline__ float wave_sum_uniform(float x) {
    x = dpp_add<0x111>(x);   // row_shr:1
    x = dpp_add<0x112>(x);   // row_shr:2
    x = dpp_add<0x114>(x);   // row_shr:4
    x = dpp_add<0x118>(x);   // row_shr:8
    x = dpp_add<0x142>(x);   // row_bcast:15
    x = dpp_add<0x143>(x);   // row_bcast:31
    return __int_as_float(__builtin_amdgcn_readlane(__float_as_int(x), 63));
}

// Main pass (R10-R13, byte-identical; measured 22.4us incl boundary =
// 5.95 TB/s, ~94% of achievable): 256 blocks x 1024 threads, 16 waves/CU.
// One wave = one row, 2 rows/wave, no barriers in the row loop, 16 float4
// loads in flight, DPP reduce, edge gradients in registers.
__global__ __launch_bounds__(1024)
__attribute__((amdgpu_waves_per_eu(4, 4)))
void conv1d_train_main(
    const float* __restrict__ x, const float* __restrict__ y,
    const float* __restrict__ kern, const float* __restrict__ bias,
    float* __restrict__ partial)
{
    __shared__ float P[KSZ];          // inclusive prefix sums of kernel
    __shared__ float sl[NWAVES][256]; // per-wave partials for block combine

    const int tid  = threadIdx.x;
    const int wave = tid >> 6;
    const int lane = tid & 63;

    if (tid < KSZ) P[tid] = kern[tid];
    __syncthreads();
#pragma unroll
    for (int off = 1; off < KSZ; off <<= 1) {   // Hillis-Steele scan
        float v = 0.f;
        if (tid < KSZ) {
            v = P[tid];
            if (tid >= off) v += P[tid - off];
        }
        __syncthreads();
        if (tid < KSZ) P[tid] = v;
        __syncthreads();
    }
    const float ksum = P[KSZ - 1];
    const float bs   = bias[0];

    // Per-lane edge-correction weights (verified R2).
    float w0, w1, w2, w3;
    if (lane < 32) {
        const int j = 4 * lane;
        w0 = P[j] - ksum; w1 = P[j + 1] - ksum;
        w2 = P[j + 2] - ksum; w3 = P[j + 3] - ksum;
    } else {
        const int m = 4 * (lane - 32) - 1;
        w0 = (m >= 0) ? -P[m] : 0.f;
        w1 = -P[m + 1]; w2 = -P[m + 2]; w3 = -P[m + 3];
    }

    float g0 = 0.f, g1 = 0.f, g2 = 0.f, g3 = 0.f;  // dconv-weighted edge accum
    float C0 = 0.f, db = 0.f;

    const int wg = blockIdx.x * NWAVES + wave;       // 0..4095

    for (int b = wg; b < BATCH; b += NB_MAIN * NWAVES) {   // 2 iterations
        const float4* xr = reinterpret_cast<const float4*>(x + (size_t)b * SEQ_LEN);
        float4 r[16];
#pragma unroll
        for (int i = 0; i < 16; ++i) r[i] = xr[i * 64 + lane];
        const float yv = y[b];                       // broadcast load

        float tot = 0.f;
#pragma unroll
        for (int i = 0; i < 16; ++i) tot += (r[i].x + r[i].y) + (r[i].z + r[i].w);

        const float4 e = (lane < 32) ? r[0] : r[15];
        const float corr = ((w0 * e.x + w1 * e.y) + (w2 * e.z + w3 * e.w));

        const float t = wave_sum_uniform(tot);       // wave-uniform scalars
        const float c = wave_sum_uniform(corr);

        const float logits = (ksum * t + c) * (1.f / (float)OUT_LEN) + bs;
        const float sig    = 1.f / (1.f + expf(-logits));
        const float dconv  = (sig - yv) * (1.f / (float)OUT_LEN);

        g0 += dconv * e.x; g1 += dconv * e.y;
        g2 += dconv * e.z; g3 += dconv * e.w;
        C0 += dconv * t;   db += dconv;
    }

    // Per-wave writeout to LDS: [0..126]=G, [127]=C0, [128..254]=H, [255]=db
    if (lane < 32) {
        const int j = 4 * lane;
        sl[wave][j]     = g0;
        sl[wave][j + 1] = g1;
        sl[wave][j + 2] = g2;
        if (j + 3 < 127) sl[wave][j + 3] = g3;   // skip unused G[127]
    } else {
        const int s0 = 4 * lane - 1;             // slot = 128 + m
        if (lane > 32) sl[wave][s0] = g0;        // lane 32 q=0 -> m=-1, skip
        sl[wave][s0 + 1] = g1;
        sl[wave][s0 + 2] = g2;
        sl[wave][s0 + 3] = g3;                   // lane 63 -> slot 254
    }
    if (lane == 0) { sl[wave][127] = C0; sl[wave][255] = db; }
    __syncthreads();
    if (tid < 256) {
        float s = 0.f;
#pragma unroll
        for (int w = 0; w < NWAVES; ++w) s += sl[w][tid];
        partial[(size_t)blockIdx.x * 256 + tid] = s;   // coalesced 1KB/block
    }
}

// Tail (single change vs R13: cheaper last-block internals).
// 16 blocks x 1024 threads; block b reduces rows 16b..16b+15 of partial
// (one float4/thread), publishes via atomicExch into its own slot (no
// zeroing, no contention, deterministic). Last arriver (counter mod 16,
// any start value) gathers with ALL 1024 threads (4 atomic loads each,
// fixed order -> deterministic), then computes pre/suf via two 128-wide
// Hillis-Steele scans (7 double-barrier steps, replaces the 127-step
// serial LDS chain), writes kernel_new (128) + bias_new (1).
__global__ __launch_bounds__(1024) void conv1d_train_tail(
    const float* __restrict__ partial, float* __restrict__ accum,
    unsigned* __restrict__ counter,
    const float* __restrict__ kern, const float* __restrict__ bias,
    float* __restrict__ out)
{
    __shared__ float slr[NWAVES][256];
    __shared__ float colsum[256];
    __shared__ float sc[256];
    __shared__ unsigned lastFlag;

    const int tid   = threadIdx.x;
    const int rsub  = tid >> 6;                 // 0..15 (row within block's 16)
    const int f4c   = tid & 63;                 // float4 column
    const int rbase = blockIdx.x * 16;

    // Phase A: one float4 per thread covers this block's 16 rows.
    const float4* p4 = reinterpret_cast<const float4*>(partial);
    const float4 v = p4[(size_t)(rbase + rsub) * 64 + f4c];
    slr[rsub][4 * f4c + 0] = v.x;
    slr[rsub][4 * f4c + 1] = v.y;
    slr[rsub][4 * f4c + 2] = v.z;
    slr[rsub][4 * f4c + 3] = v.w;
    __syncthreads();

    if (tid < 256) {
        float s = 0.f;
#pragma unroll
        for (int w = 0; w < NWAVES; ++w) s += slr[w][tid];
        atomicExch(&accum[(size_t)blockIdx.x * 256 + tid], s);  // publish
    }
    __syncthreads();            // drains vmcnt: exchanges retired

    if (tid == 0) {
        __threadfence();
        const unsigned old = atomicAdd(counter, 1u);
        lastFlag = ((old & 15u) == 15u) ? 1u : 0u;
    }
    __syncthreads();
    if (!lastFlag) return;

    // Last block: gather with all 1024 threads (4 slots each, fixed order).
    {
        const int w4 = tid >> 8;                // 0..3
        const int c  = tid & 255;
        float s = 0.f;
#pragma unroll
        for (int w = 0; w < 4; ++w)
            s += __hip_atomic_load(&accum[(size_t)(w4 + 4 * w) * 256 + c],
                                   __ATOMIC_RELAXED, __HIP_MEMORY_SCOPE_AGENT);
        slr[w4][c] = s;
    }
    __syncthreads();
    if (tid < 256)
        colsum[tid] = (slr[0][tid] + slr[1][tid]) + (slr[2][tid] + slr[3][tid]);
    __syncthreads();

    // pre/suf via two simultaneous 128-wide Hillis-Steele inclusive scans:
    // lower half scans g = colsum[0..126] (127 slot = C0 -> 0),
    // upper half scans h = colsum[128..254] (255 slot = db -> 0).
    float gh = 0.f;
    if (tid < 256) {
        gh = colsum[tid];
        if (tid == 127 || tid == 255) gh = 0.f;
        sc[tid] = gh;
    }
    __syncthreads();
#pragma unroll
    for (int off = 1; off < 128; off <<= 1) {
        float add = 0.f;
        if (tid < 256 && (tid & 127) >= off) add = sc[tid - off];
        __syncthreads();
        if (tid < 256) sc[tid] += add;
        __syncthreads();
    }

    if (tid < 128) {
        const float C0   = colsum[127];
        const float TH   = sc[255];              // sum of all h
        const float pre  = sc[tid] - gh;         // exclusive prefix of g
        const float inch = sc[128 + tid];
        const float h_t  = (tid < 127) ? colsum[128 + tid] : 0.f;
        const float suf  = TH - (inch - h_t);    // sum h[j], j >= tid
        const float dk = (C0 - pre - suf) * (1.f / (float)BATCH);
        out[tid] = kern[tid] - dk;
    }
    if (tid == 0) {
        const float dbo = colsum[255] * ((float)OUT_LEN / (float)BATCH);
        out[128] = bias[0] - dbo;
    }
}

extern "C" void kernel_launch(void* const* d_in, const int* in_sizes, int n_in,
                              void* d_out, int out_size, void* d_ws, size_t ws_size,
                              hipStream_t stream) {
    (void)in_sizes; (void)n_in; (void)out_size; (void)ws_size;
    const float* x    = (const float*)d_in[0];
    const float* y    = (const float*)d_in[1];
    const float* kern = (const float*)d_in[2];
    const float* bias = (const float*)d_in[3];
    float* out = (float*)d_out;

    // ws layout: partial[256*256] floats (256KB), accum[16*256] floats
    // (16KB), counter (4B). partial/accum fully overwritten every launch;
    // counter works mod 16 for any start value — nothing needs init.
    float*    partial = (float*)d_ws;
    float*    accum   = partial + (size_t)NB_MAIN * 256;
    unsigned* counter = (unsigned*)(accum + (size_t)TAIL_NB * 256);

    hipLaunchKernelGGL(conv1d_train_main, dim3(NB_MAIN), dim3(1024), 0, stream,
                       x, y, kern, bias, partial);
    hipLaunchKernelGGL(conv1d_train_tail, dim3(TAIL_NB), dim3(1024), 0, stream,
                       partial, accum, counter, kern, bias, out);
}